// Round 10
// baseline (308.284 us; speedup 1.0000x reference)
//
#include <hip/hip_runtime.h>

#define NN 50000
#define NE 800000
#define FIN 512
#define HID 128
#define NOUT 40
#define H2P 64          // padded h2 row (elements) -> 128B aligned rows
#define CAP 64          // bucket capacity per row (max degree ~36 for Poisson-16)
#define NXS 16          // nxt counter stride (ints) -> one counter per 64B line
#define GB1 1563        // gemm1 blocks = ceil(NN/32)  (BM1=32: 6.1 blocks/CU tail)
#define EPB 2048        // edges per scatter block (8 per thread, ILP)
#define SB  391         // scatter blocks = ceil(NE/EPB)
#define MB  782         // maskpack blocks = ceil(NN*4/256)

typedef __bf16 v8bf __attribute__((ext_vector_type(8)));
typedef float  v4f  __attribute__((ext_vector_type(4)));
typedef float  v2f  __attribute__((ext_vector_type(2)));
typedef unsigned short us8 __attribute__((ext_vector_type(8)));
typedef unsigned short us4 __attribute__((ext_vector_type(4)));
typedef unsigned int   u32x4 __attribute__((ext_vector_type(4)));
typedef unsigned int   u32x2 __attribute__((ext_vector_type(2)));

static __device__ __forceinline__ unsigned short f2bf(float f) {
  union { float f; unsigned int u; } v; v.f = f;
  unsigned int r = v.u + 0x7FFFu + ((v.u >> 16) & 1u);
  return (unsigned short)(r >> 16);
}
static __device__ __forceinline__ float bf2f(unsigned short s) {
  union { unsigned int u; float f; } v; v.u = ((unsigned int)s) << 16;
  return v.f;
}
static __device__ __forceinline__ float u2f(unsigned int u) {
  union { unsigned int u; float f; } v; v.u = u;
  return v.f;
}
// dword of 2 bf16 -> float2 {lo, hi}; 2 VALU ops, feeds v_pk_fma_f32
static __device__ __forceinline__ v2f bfp2f(unsigned int u) {
  v2f r; r.x = u2f(u << 16); r.y = u2f(u & 0xFFFF0000u); return r;
}

// ---------- W1 [FIN][HID] f32 -> W1t [HID][FIN] bf16 ; also zero nxt ----------
__global__ void k_w1t(const float* __restrict__ W1, unsigned short* __restrict__ W1t,
                      int* __restrict__ nxt) {
  int id = blockIdx.x * 256 + threadIdx.x;   // 65536 threads
  int k = id >> 7;
  int n = id & 127;
  W1t[n * FIN + k] = f2bf(W1[k * HID + n]);
  if (id < NN) nxt[(size_t)id * NXS] = 0;    // one counter per 64B line
}

// ---- fused: GEMM1 [0,GB1) | scatter [GB1,GB1+SB) | maskpack [GB1+SB,+MB) ----
// R9 lessons: (a) 37% occupancy is GRID-limited (782 gemm1 blocks / 256 CUs =
// 3.05/CU in the tail) -- not LDS-limited; (b) B must stay LDS-staged (B-from-
// L2 put ~200cyc loads on the MFMA path, 80->86us). Fix: BM1 64->32 => 1563
// gemm1 blocks = 6.1/CU tail residency, 2x waves to hide barrier+L2 latency.
// Staging/barrier structure R3-exact, re-indexed for the 32-row tile.
#define BM1 32
#define BK1 64
#define BKP1 72
__global__ __launch_bounds__(256) void k_fused(
    const float* __restrict__ x, const unsigned short* __restrict__ W1t,
    unsigned short* __restrict__ hb0,
    const int* __restrict__ src, const int* __restrict__ dst,
    const float* __restrict__ w, int* __restrict__ nxt,
    unsigned int* __restrict__ bkt,
    const float* __restrict__ mask, unsigned int* __restrict__ mpk) {
  __shared__ unsigned short As[BM1 * BKP1];   // 4608 B
  __shared__ unsigned short Bs[HID * BKP1];   // 18432 B  (23 KB total -> 7 blk/CU cap)
  const int t = threadIdx.x;

  if (blockIdx.x >= GB1 + SB) {
    // ---------------- maskpack body: 4 uint words per row ----------------
    int id = (blockIdx.x - (GB1 + SB)) * 256 + t;
    if (id < NN * 4) {
      int row = id >> 2, seg = id & 3;
      const float4* mp = (const float4*)(mask + (size_t)row * HID + seg * 32);
      unsigned int bits = 0;
      #pragma unroll
      for (int q = 0; q < 8; ++q) {
        float4 v = mp[q];
        bits |= (v.x != 0.f ? 1u : 0u) << (q * 4);
        bits |= (v.y != 0.f ? 1u : 0u) << (q * 4 + 1);
        bits |= (v.z != 0.f ? 1u : 0u) << (q * 4 + 2);
        bits |= (v.w != 0.f ? 1u : 0u) << (q * 4 + 3);
      }
      mpk[(size_t)row * 4 + seg] = bits;
    }
    return;
  }

  if (blockIdx.x >= GB1) {
    // -------- scatter body: 8 edges/thread, independent atomics --------
    const int base = (blockIdx.x - GB1) * EPB + t;
    int   ii[8]; unsigned int pk[8]; int ok[8];
    #pragma unroll
    for (int k = 0; k < 8; ++k) {
      int e = base + k * 256;
      ok[k] = (e < NE);
      int ec = ok[k] ? e : (NE - 1);
      ii[k] = dst[ec];
      pk[k] = (unsigned int)src[ec] | ((unsigned int)f2bf(w[ec]) << 16);
    }
    int p[8];
    #pragma unroll
    for (int k = 0; k < 8; ++k)
      p[k] = ok[k] ? atomicAdd(&nxt[(size_t)ii[k] * NXS], 1) : CAP;
    #pragma unroll
    for (int k = 0; k < 8; ++k)
      if (p[k] < CAP) bkt[(size_t)ii[k] * CAP + p[k]] = pk[k];
    return;
  }

  // ---------------- gemm1 body: 32-row tile, R3-style staging ----------------
  const int r0 = blockIdx.x * BM1;
  const int wave = t >> 6, lane = t & 63;
  const int quad = lane >> 4, mr = lane & 15;
  const int ncol0 = wave * 32;            // each wave owns a 32-col slice

  const int ar = t >> 3, aq = t & 7;      // 32 rows x 8 threads/row
  int grow = r0 + ar; if (grow > NN - 1) grow = NN - 1;
  const float4* xrow = (const float4*)(x + (size_t)grow * FIN);
  const int bn = t >> 1, bh = t & 1;      // 128 cols x 2 threads/col (as R3)

  const v4f vzero = {0.f, 0.f, 0.f, 0.f};
  v4f acc[2][2];
  #pragma unroll
  for (int mi = 0; mi < 2; ++mi)
    #pragma unroll
    for (int j = 0; j < 2; ++j) acc[mi][j] = vzero;

  for (int k0 = 0; k0 < FIN; k0 += BK1) {
    float4 va[2];
    #pragma unroll
    for (int i = 0; i < 2; ++i) va[i] = xrow[(k0 >> 2) + aq + i * 8];
    us8 vb[4];
    const us8* bp = (const us8*)(W1t + bn * FIN + k0 + bh * 32);
    #pragma unroll
    for (int i = 0; i < 4; ++i) vb[i] = bp[i];

    __syncthreads();
    #pragma unroll
    for (int i = 0; i < 2; ++i) {
      us4 s; s.x = f2bf(va[i].x); s.y = f2bf(va[i].y);
             s.z = f2bf(va[i].z); s.w = f2bf(va[i].w);
      *(us4*)&As[ar * BKP1 + aq * 4 + i * 32] = s;
    }
    #pragma unroll
    for (int i = 0; i < 4; ++i)
      *(us8*)&Bs[bn * BKP1 + bh * 32 + i * 8] = vb[i];
    __syncthreads();

    #pragma unroll
    for (int ks = 0; ks < BK1; ks += 32) {
      v8bf a0 = *(const v8bf*)&As[(mr) * BKP1 + ks + quad * 8];
      v8bf a1 = *(const v8bf*)&As[(16 + mr) * BKP1 + ks + quad * 8];
      #pragma unroll
      for (int j = 0; j < 2; ++j) {
        v8bf b = *(const v8bf*)&Bs[(ncol0 + j * 16 + mr) * BKP1 + ks + quad * 8];
        acc[0][j] = __builtin_amdgcn_mfma_f32_16x16x32_bf16(a0, b, acc[0][j], 0, 0, 0);
        acc[1][j] = __builtin_amdgcn_mfma_f32_16x16x32_bf16(a1, b, acc[1][j], 0, 0, 0);
      }
    }
  }

  #pragma unroll
  for (int mi = 0; mi < 2; ++mi)
    #pragma unroll
    for (int j = 0; j < 2; ++j)
      #pragma unroll
      for (int rr = 0; rr < 4; ++rr) {
        int row = r0 + mi * 16 + quad * 4 + rr;
        int col = ncol0 + j * 16 + mr;
        if (row < NN) hb0[(size_t)row * HID + col] = f2bf(acc[mi][j][rr]);
      }
}

// ---------- SpMM1: 4 groups x 16 lanes, 4 edges/wave, bf16 16B row-gather ----------
// R3-exact pk_fma form. R7 lesson: f32 rows doubled gather bytes, -24us. bf16 stays.
__global__ __launch_bounds__(256) void k_spmm1(const unsigned short* __restrict__ hb0,
                                               const int* __restrict__ nxt,
                                               const unsigned int* __restrict__ bkt,
                                               const float* __restrict__ b1,
                                               const unsigned int* __restrict__ mpk,
                                               unsigned short* __restrict__ hb1) {
  const int t = threadIdx.x, lane = t & 63, wv = t >> 6;
  const int g = lane >> 4, ql = lane & 15;
  const int i = blockIdx.x * 4 + wv;
  const int c0 = ql * 8;
  int nE = nxt[(size_t)i * NXS]; if (nE > CAP) nE = CAP;
  const int m = (nE + 3 - g) >> 2;             // edges handled by this group
  const unsigned int* ep = bkt + (size_t)i * CAP + g;

  const v2f z2 = {0.f, 0.f};
  v2f a0p[4] = {z2, z2, z2, z2};
  v2f a1p[4] = {z2, z2, z2, z2};
  int j = 0;
  for (; j + 3 < m; j += 4) {                  // 16 gathers in flight per wave
    unsigned int p0 = ep[4*j], p1 = ep[4*j+4], p2 = ep[4*j+8], p3 = ep[4*j+12];
    int s0 = p0 & 0xFFFF, s1 = p1 & 0xFFFF, s2 = p2 & 0xFFFF, s3 = p3 & 0xFFFF;
    v2f w0, w1, w2, w3;
    w0.x = w0.y = bf2f((unsigned short)(p0 >> 16));
    w1.x = w1.y = bf2f((unsigned short)(p1 >> 16));
    w2.x = w2.y = bf2f((unsigned short)(p2 >> 16));
    w3.x = w3.y = bf2f((unsigned short)(p3 >> 16));
    u32x4 h0 = *(const u32x4*)&hb0[(size_t)s0 * HID + c0];
    u32x4 h1 = *(const u32x4*)&hb0[(size_t)s1 * HID + c0];
    u32x4 h2 = *(const u32x4*)&hb0[(size_t)s2 * HID + c0];
    u32x4 h3 = *(const u32x4*)&hb0[(size_t)s3 * HID + c0];
    #pragma unroll
    for (int d = 0; d < 4; ++d) {
      a0p[d] += w0 * bfp2f(h0[d]);
      a1p[d] += w1 * bfp2f(h1[d]);
      a0p[d] += w2 * bfp2f(h2[d]);
      a1p[d] += w3 * bfp2f(h3[d]);
    }
  }
  for (; j < m; ++j) {
    unsigned int p = ep[4*j];
    int s = p & 0xFFFF;
    v2f w; w.x = w.y = bf2f((unsigned short)(p >> 16));
    u32x4 h = *(const u32x4*)&hb0[(size_t)s * HID + c0];
    #pragma unroll
    for (int d = 0; d < 4; ++d) a0p[d] += w * bfp2f(h[d]);
  }
  float v[8];
  #pragma unroll
  for (int d = 0; d < 4; ++d) {
    v2f s = a0p[d] + a1p[d];
    v[2*d] = s.x; v[2*d+1] = s.y;
  }
  #pragma unroll
  for (int k = 0; k < 8; ++k) {
    v[k] += __shfl_xor(v[k], 16);
    v[k] += __shfl_xor(v[k], 32);
  }
  if (g == 0) {
    unsigned int word = mpk[(size_t)i * 4 + (ql >> 2)];
    unsigned int byte = (word >> ((ql & 3) * 8)) & 0xFFu;
    const float4 bbA = *(const float4*)&b1[c0];
    const float4 bbB = *(const float4*)&b1[c0 + 4];
    float bb[8] = {bbA.x, bbA.y, bbA.z, bbA.w, bbB.x, bbB.y, bbB.z, bbB.w};
    us8 o;
    #pragma unroll
    for (int k = 0; k < 8; ++k) {
      float r = ((byte >> k) & 1u) ? fmaxf(v[k] + bb[k], 0.f) * 2.0f : 0.f;
      o[k] = f2bf(r);
    }
    *(us8*)&hb1[(size_t)i * HID + c0] = o;
  }
}

// ------ GEMM2: h2b[NN][H2P=64] = bf16(hb1 @ W2), rows 128B-aligned ------
#define BKP2 136
__global__ __launch_bounds__(256) void k_gemm2(const unsigned short* __restrict__ hb1,
                                               const float* __restrict__ W2,
                                               unsigned short* __restrict__ h2b) {
  __shared__ unsigned short As[64 * BKP2];
  __shared__ unsigned short Bs[48 * BKP2];
  const int t = threadIdx.x;
  const int r0 = blockIdx.x * 64;
  const int wave = t >> 6, lane = t & 63;
  const int quad = lane >> 4, mr = lane & 15;
  const int mrow0 = wave * 16;

  const int ar = t >> 2, aq = t & 3;
  int grow = r0 + ar; if (grow > NN - 1) grow = NN - 1;
  const us8* hrow = (const us8*)(hb1 + (size_t)grow * HID);
  #pragma unroll
  for (int i = 0; i < 4; ++i) {
    us8 v = hrow[aq + i * 4];
    *(us8*)&As[ar * BKP2 + aq * 8 + i * 32] = v;
  }
  if (t < 192) {
    int n = t >> 2, q = t & 3;
    #pragma unroll
    for (int kk = 0; kk < 32; ++kk) {
      int k = q * 32 + kk;
      float val = (n < NOUT) ? W2[k * NOUT + n] : 0.f;
      Bs[n * BKP2 + k] = f2bf(val);
    }
  }
  __syncthreads();

  const v4f vzero = {0.f, 0.f, 0.f, 0.f};
  v4f acc[3] = {vzero, vzero, vzero};
  #pragma unroll
  for (int ks = 0; ks < HID; ks += 32) {
    v8bf a = *(const v8bf*)&As[(mrow0 + mr) * BKP2 + ks + quad * 8];
    #pragma unroll
    for (int j = 0; j < 3; ++j) {
      v8bf b = *(const v8bf*)&Bs[(j * 16 + mr) * BKP2 + ks + quad * 8];
      acc[j] = __builtin_amdgcn_mfma_f32_16x16x32_bf16(a, b, acc[j], 0, 0, 0);
    }
  }
  #pragma unroll
  for (int j = 0; j < 3; ++j)
    #pragma unroll
    for (int rr = 0; rr < 4; ++rr) {
      int row = r0 + mrow0 + quad * 4 + rr;
      int col = j * 16 + mr;
      if (row < NN && col < NOUT) h2b[(size_t)row * H2P + col] = f2bf(acc[j][rr]);
    }
}

// ---------- SpMM2: 4 groups x 16 lanes (10 active), bf16 8B gathers ----------
__global__ __launch_bounds__(256) void k_spmm2(const unsigned short* __restrict__ h2b,
                                               const int* __restrict__ nxt,
                                               const unsigned int* __restrict__ bkt,
                                               const float* __restrict__ b2,
                                               float* __restrict__ out) {
  const int t = threadIdx.x, lane = t & 63;
  const int g = lane >> 4, ql = lane & 15;
  const int i = blockIdx.x * 4 + (t >> 6);
  if (i >= NN) return;
  const int act = (ql < 10);
  const int c0 = act ? ql * 4 : 0;             // clamp inactive lanes in-bounds
  int nE = nxt[(size_t)i * NXS]; if (nE > CAP) nE = CAP;
  const int m = (nE + 3 - g) >> 2;
  const unsigned int* ep = bkt + (size_t)i * CAP + g;

  const v2f z2 = {0.f, 0.f};
  v2f a0p[2] = {z2, z2};
  v2f a1p[2] = {z2, z2};
  int j = 0;
  for (; j + 3 < m; j += 4) {
    unsigned int p0 = ep[4*j], p1 = ep[4*j+4], p2 = ep[4*j+8], p3 = ep[4*j+12];
    int s0 = p0 & 0xFFFF, s1 = p1 & 0xFFFF, s2 = p2 & 0xFFFF, s3 = p3 & 0xFFFF;
    v2f w0, w1, w2, w3;
    w0.x = w0.y = bf2f((unsigned short)(p0 >> 16));
    w1.x = w1.y = bf2f((unsigned short)(p1 >> 16));
    w2.x = w2.y = bf2f((unsigned short)(p2 >> 16));
    w3.x = w3.y = bf2f((unsigned short)(p3 >> 16));
    u32x2 h0 = *(const u32x2*)&h2b[(size_t)s0 * H2P + c0];
    u32x2 h1 = *(const u32x2*)&h2b[(size_t)s1 * H2P + c0];
    u32x2 h2 = *(const u32x2*)&h2b[(size_t)s2 * H2P + c0];
    u32x2 h3 = *(const u32x2*)&h2b[(size_t)s3 * H2P + c0];
    #pragma unroll
    for (int d = 0; d < 2; ++d) {
      a0p[d] += w0 * bfp2f(h0[d]);
      a1p[d] += w1 * bfp2f(h1[d]);
      a0p[d] += w2 * bfp2f(h2[d]);
      a1p[d] += w3 * bfp2f(h3[d]);
    }
  }
  for (; j < m; ++j) {
    unsigned int p = ep[4*j];
    int s = p & 0xFFFF;
    v2f w; w.x = w.y = bf2f((unsigned short)(p >> 16));
    u32x2 h = *(const u32x2*)&h2b[(size_t)s * H2P + c0];
    #pragma unroll
    for (int d = 0; d < 2; ++d) a0p[d] += w * bfp2f(h[d]);
  }
  float v[4];
  #pragma unroll
  for (int d = 0; d < 2; ++d) {
    v2f s = a0p[d] + a1p[d];
    v[2*d] = s.x; v[2*d+1] = s.y;
  }
  #pragma unroll
  for (int k = 0; k < 4; ++k) {
    v[k] += __shfl_xor(v[k], 16);
    v[k] += __shfl_xor(v[k], 32);
  }
  if (g == 0 && act) {
    const float4 bb = *(const float4*)&b2[c0];
    float4 o;
    o.x = v[0] + bb.x;
    o.y = v[1] + bb.y;
    o.z = v[2] + bb.z;
    o.w = v[3] + bb.w;
    *(float4*)&out[(size_t)i * NOUT + c0] = o;
  }
}

extern "C" void kernel_launch(void* const* d_in, const int* in_sizes, int n_in,
                              void* d_out, int out_size, void* d_ws, size_t ws_size,
                              hipStream_t stream) {
  const float* x   = (const float*)d_in[0];
  const float* W1  = (const float*)d_in[1];
  const float* b1  = (const float*)d_in[2];
  const float* W2  = (const float*)d_in[3];
  const float* b2  = (const float*)d_in[4];
  const float* ew  = (const float*)d_in[5];
  const float* msk = (const float*)d_in[6];
  const int* esrc  = (const int*)d_in[7];
  const int* edst  = (const int*)d_in[8];
  float* out = (float*)d_out;

  char* ws = (char*)d_ws;
  unsigned short* hb0 = (unsigned short*)ws; ws += (size_t)NN * HID * 2;   // 12.8 MB
  unsigned short* hb1 = (unsigned short*)ws; ws += (size_t)NN * HID * 2;   // 12.8 MB
  unsigned short* h2b = (unsigned short*)ws; ws += (size_t)NN * H2P * 2;   // 6.4 MB
  unsigned short* W1t = (unsigned short*)ws; ws += (size_t)HID * FIN * 2;  // 128 KB
  unsigned int* bkt   = (unsigned int*)ws;   ws += (size_t)NN * CAP * 4;   // 12.8 MB
  unsigned int* mpk   = (unsigned int*)ws;   ws += (size_t)NN * 4 * 4;     // 800 KB
  int* nxt            = (int*)ws;            ws += (size_t)NN * NXS * 4;   // 3.2 MB

  k_w1t  <<<(FIN * HID) / 256, 256, 0, stream>>>(W1, W1t, nxt);
  k_fused<<<GB1 + SB + MB, 256, 0, stream>>>(x, W1t, hb0,
                                             esrc, edst, ew, nxt, bkt,
                                             msk, mpk);
  k_spmm1<<<NN / 4, 256, 0, stream>>>(hb0, nxt, bkt, b1, mpk, hb1);
  k_gemm2<<<(NN + 63) / 64, 256, 0, stream>>>(hb1, W2, h2b);
  k_spmm2<<<(NN + 3) / 4, 256, 0, stream>>>(h2b, nxt, bkt, b2, out);
}

// Round 11
// 292.168 us; speedup vs baseline: 1.0552x; 1.0552x over previous
//
#include <hip/hip_runtime.h>

#define NN 50000
#define NE 800000
#define FIN 512
#define HID 128
#define NOUT 40
#define H2P 64          // padded h2 row (elements) -> 128B aligned rows
#define CAP 64          // bucket capacity per row (max degree ~36 for Poisson-16)
#define NXS 16          // nxt counter stride (ints) -> one counter per 64B line
#define GB1 782         // gemm1 blocks = ceil(NN/64)  (R3-exact; BM1=32 regressed R10)
#define EPB 2048        // edges per scatter block (8 per thread, ILP)
#define SB  391         // scatter blocks = ceil(NE/EPB)
#define MB  782         // maskpack blocks = ceil(NN*4/256)

typedef __bf16 v8bf __attribute__((ext_vector_type(8)));
typedef float  v4f  __attribute__((ext_vector_type(4)));
typedef float  v2f  __attribute__((ext_vector_type(2)));
typedef unsigned short us8 __attribute__((ext_vector_type(8)));
typedef unsigned short us4 __attribute__((ext_vector_type(4)));
typedef unsigned int   u32x4 __attribute__((ext_vector_type(4)));
typedef unsigned int   u32x2 __attribute__((ext_vector_type(2)));

static __device__ __forceinline__ unsigned short f2bf(float f) {
  union { float f; unsigned int u; } v; v.f = f;
  unsigned int r = v.u + 0x7FFFu + ((v.u >> 16) & 1u);
  return (unsigned short)(r >> 16);
}
static __device__ __forceinline__ float bf2f(unsigned short s) {
  union { unsigned int u; float f; } v; v.u = ((unsigned int)s) << 16;
  return v.f;
}
static __device__ __forceinline__ float u2f(unsigned int u) {
  union { unsigned int u; float f; } v; v.u = u;
  return v.f;
}
// dword of 2 bf16 -> float2 {lo, hi}; 2 VALU ops, feeds v_pk_fma_f32
static __device__ __forceinline__ v2f bfp2f(unsigned int u) {
  v2f r; r.x = u2f(u << 16); r.y = u2f(u & 0xFFFF0000u); return r;
}

// ---------- W1 [FIN][HID] f32 -> W1t [HID][FIN] bf16 ; also zero nxt ----------
__global__ void k_w1t(const float* __restrict__ W1, unsigned short* __restrict__ W1t,
                      int* __restrict__ nxt) {
  int id = blockIdx.x * 256 + threadIdx.x;   // 65536 threads
  int k = id >> 7;
  int n = id & 127;
  W1t[n * FIN + k] = f2bf(W1[k * HID + n]);
  if (id < NN) nxt[(size_t)id * NXS] = 0;    // one counter per 64B line
}

// ---- fused: GEMM1 [0,GB1) | scatter [GB1,GB1+SB) | maskpack [GB1+SB,+MB) ----
// R3-exact structure (measured 80us; every deviation regressed: R4 no-LDS
// 109us, R9 B-from-L2 86us, R10 BM1=32 90.5us). Only change vs R3: the
// bucket slot is GROUP-SWIZZLED ((p&3)*16 + (p>>2), bijective on [0,64)) so
// the spmm kernels can read 4 edge-words with one u32x4 load.
#define BM1 64
#define BK1 64
#define BKP1 72
__global__ __launch_bounds__(256) void k_fused(
    const float* __restrict__ x, const unsigned short* __restrict__ W1t,
    unsigned short* __restrict__ hb0,
    const int* __restrict__ src, const int* __restrict__ dst,
    const float* __restrict__ w, int* __restrict__ nxt,
    unsigned int* __restrict__ bkt,
    const float* __restrict__ mask, unsigned int* __restrict__ mpk) {
  __shared__ unsigned short As[BM1 * BKP1];   // 9216 B
  __shared__ unsigned short Bs[HID * BKP1];   // 18432 B
  const int t = threadIdx.x;

  if (blockIdx.x >= GB1 + SB) {
    // ---------------- maskpack body: 4 uint words per row ----------------
    int id = (blockIdx.x - (GB1 + SB)) * 256 + t;
    if (id < NN * 4) {
      int row = id >> 2, seg = id & 3;
      const float4* mp = (const float4*)(mask + (size_t)row * HID + seg * 32);
      unsigned int bits = 0;
      #pragma unroll
      for (int q = 0; q < 8; ++q) {
        float4 v = mp[q];
        bits |= (v.x != 0.f ? 1u : 0u) << (q * 4);
        bits |= (v.y != 0.f ? 1u : 0u) << (q * 4 + 1);
        bits |= (v.z != 0.f ? 1u : 0u) << (q * 4 + 2);
        bits |= (v.w != 0.f ? 1u : 0u) << (q * 4 + 3);
      }
      mpk[(size_t)row * 4 + seg] = bits;
    }
    return;
  }

  if (blockIdx.x >= GB1) {
    // -------- scatter body: 8 edges/thread, independent atomics --------
    const int base = (blockIdx.x - GB1) * EPB + t;
    int   ii[8]; unsigned int pk[8]; int ok[8];
    #pragma unroll
    for (int k = 0; k < 8; ++k) {
      int e = base + k * 256;
      ok[k] = (e < NE);
      int ec = ok[k] ? e : (NE - 1);
      ii[k] = dst[ec];
      pk[k] = (unsigned int)src[ec] | ((unsigned int)f2bf(w[ec]) << 16);
    }
    int p[8];
    #pragma unroll
    for (int k = 0; k < 8; ++k)
      p[k] = ok[k] ? atomicAdd(&nxt[(size_t)ii[k] * NXS], 1) : CAP;
    #pragma unroll
    for (int k = 0; k < 8; ++k)
      if (p[k] < CAP) {
        int slot = ((p[k] & 3) << 4) + (p[k] >> 2);   // group-contiguous layout
        bkt[(size_t)ii[k] * CAP + slot] = pk[k];
      }
    return;
  }

  // ---------------- gemm1 body (R3-exact) ----------------
  const int r0 = blockIdx.x * BM1;
  const int wave = t >> 6, lane = t & 63;
  const int quad = lane >> 4, mr = lane & 15;
  const int mrow0 = (wave & 1) * 32;
  const int ncol0 = (wave >> 1) * 64;

  const int ar = t >> 2, aq = t & 3;
  int grow = r0 + ar; if (grow > NN - 1) grow = NN - 1;
  const float4* xrow = (const float4*)(x + (size_t)grow * FIN);
  const int bn = t >> 1, bh = t & 1;

  const v4f vzero = {0.f, 0.f, 0.f, 0.f};
  v4f acc[2][4];
  #pragma unroll
  for (int mi = 0; mi < 2; ++mi)
    #pragma unroll
    for (int j = 0; j < 4; ++j) acc[mi][j] = vzero;

  for (int k0 = 0; k0 < FIN; k0 += BK1) {
    float4 va[4];
    #pragma unroll
    for (int i = 0; i < 4; ++i) va[i] = xrow[(k0 >> 2) + aq + i * 4];
    us8 vb[4];
    const us8* bp = (const us8*)(W1t + bn * FIN + k0 + bh * 32);
    #pragma unroll
    for (int i = 0; i < 4; ++i) vb[i] = bp[i];

    __syncthreads();
    #pragma unroll
    for (int i = 0; i < 4; ++i) {
      us4 s; s.x = f2bf(va[i].x); s.y = f2bf(va[i].y);
             s.z = f2bf(va[i].z); s.w = f2bf(va[i].w);
      *(us4*)&As[ar * BKP1 + aq * 4 + i * 16] = s;
    }
    #pragma unroll
    for (int i = 0; i < 4; ++i)
      *(us8*)&Bs[bn * BKP1 + bh * 32 + i * 8] = vb[i];
    __syncthreads();

    #pragma unroll
    for (int ks = 0; ks < BK1; ks += 32) {
      v8bf a0 = *(const v8bf*)&As[(mrow0 + mr) * BKP1 + ks + quad * 8];
      v8bf a1 = *(const v8bf*)&As[(mrow0 + 16 + mr) * BKP1 + ks + quad * 8];
      #pragma unroll
      for (int j = 0; j < 4; ++j) {
        v8bf b = *(const v8bf*)&Bs[(ncol0 + j * 16 + mr) * BKP1 + ks + quad * 8];
        acc[0][j] = __builtin_amdgcn_mfma_f32_16x16x32_bf16(a0, b, acc[0][j], 0, 0, 0);
        acc[1][j] = __builtin_amdgcn_mfma_f32_16x16x32_bf16(a1, b, acc[1][j], 0, 0, 0);
      }
    }
  }

  #pragma unroll
  for (int mi = 0; mi < 2; ++mi)
    #pragma unroll
    for (int j = 0; j < 4; ++j)
      #pragma unroll
      for (int rr = 0; rr < 4; ++rr) {
        int row = r0 + mrow0 + mi * 16 + quad * 4 + rr;
        int col = ncol0 + j * 16 + mr;
        if (row < NN) hb0[(size_t)row * HID + col] = f2bf(acc[mi][j][rr]);
      }
}

// ---------- SpMM1: 4 groups x 16 lanes, 4 edges/wave, bf16 16B row-gather ----------
// R3-exact pk_fma core; bucket words for this group are now CONTIGUOUS
// (group-swizzled layout) -> the 4-edge unroll loads them with ONE u32x4
// instead of 4 scalar loads, shortening the dependent ep->row chain.
__global__ __launch_bounds__(256) void k_spmm1(const unsigned short* __restrict__ hb0,
                                               const int* __restrict__ nxt,
                                               const unsigned int* __restrict__ bkt,
                                               const float* __restrict__ b1,
                                               const unsigned int* __restrict__ mpk,
                                               unsigned short* __restrict__ hb1) {
  const int t = threadIdx.x, lane = t & 63, wv = t >> 6;
  const int g = lane >> 4, ql = lane & 15;
  const int i = blockIdx.x * 4 + wv;
  const int c0 = ql * 8;
  int nE = nxt[(size_t)i * NXS]; if (nE > CAP) nE = CAP;
  const int m = (nE + 3 - g) >> 2;             // edges handled by this group
  const unsigned int* ep = bkt + (size_t)i * CAP + g * 16;   // contiguous words

  const v2f z2 = {0.f, 0.f};
  v2f a0p[4] = {z2, z2, z2, z2};
  v2f a1p[4] = {z2, z2, z2, z2};
  int j = 0;
  for (; j + 3 < m; j += 4) {                  // 16 gathers in flight per wave
    u32x4 pw = *(const u32x4*)&ep[j];          // one 16B load: 4 edge words
    int s0 = pw[0] & 0xFFFF, s1 = pw[1] & 0xFFFF;
    int s2 = pw[2] & 0xFFFF, s3 = pw[3] & 0xFFFF;
    v2f w0, w1, w2, w3;
    w0.x = w0.y = bf2f((unsigned short)(pw[0] >> 16));
    w1.x = w1.y = bf2f((unsigned short)(pw[1] >> 16));
    w2.x = w2.y = bf2f((unsigned short)(pw[2] >> 16));
    w3.x = w3.y = bf2f((unsigned short)(pw[3] >> 16));
    u32x4 h0 = *(const u32x4*)&hb0[(size_t)s0 * HID + c0];
    u32x4 h1 = *(const u32x4*)&hb0[(size_t)s1 * HID + c0];
    u32x4 h2 = *(const u32x4*)&hb0[(size_t)s2 * HID + c0];
    u32x4 h3 = *(const u32x4*)&hb0[(size_t)s3 * HID + c0];
    #pragma unroll
    for (int d = 0; d < 4; ++d) {
      a0p[d] += w0 * bfp2f(h0[d]);
      a1p[d] += w1 * bfp2f(h1[d]);
      a0p[d] += w2 * bfp2f(h2[d]);
      a1p[d] += w3 * bfp2f(h3[d]);
    }
  }
  for (; j < m; ++j) {
    unsigned int p = ep[j];
    int s = p & 0xFFFF;
    v2f w; w.x = w.y = bf2f((unsigned short)(p >> 16));
    u32x4 h = *(const u32x4*)&hb0[(size_t)s * HID + c0];
    #pragma unroll
    for (int d = 0; d < 4; ++d) a0p[d] += w * bfp2f(h[d]);
  }
  float v[8];
  #pragma unroll
  for (int d = 0; d < 4; ++d) {
    v2f s = a0p[d] + a1p[d];
    v[2*d] = s.x; v[2*d+1] = s.y;
  }
  #pragma unroll
  for (int k = 0; k < 8; ++k) {
    v[k] += __shfl_xor(v[k], 16);
    v[k] += __shfl_xor(v[k], 32);
  }
  if (g == 0) {
    unsigned int word = mpk[(size_t)i * 4 + (ql >> 2)];
    unsigned int byte = (word >> ((ql & 3) * 8)) & 0xFFu;
    const float4 bbA = *(const float4*)&b1[c0];
    const float4 bbB = *(const float4*)&b1[c0 + 4];
    float bb[8] = {bbA.x, bbA.y, bbA.z, bbA.w, bbB.x, bbB.y, bbB.z, bbB.w};
    us8 o;
    #pragma unroll
    for (int k = 0; k < 8; ++k) {
      float r = ((byte >> k) & 1u) ? fmaxf(v[k] + bb[k], 0.f) * 2.0f : 0.f;
      o[k] = f2bf(r);
    }
    *(us8*)&hb1[(size_t)i * HID + c0] = o;
  }
}

// ------ GEMM2: h2b[NN][H2P=64] = bf16(hb1 @ W2), rows 128B-aligned ------
#define BKP2 136
__global__ __launch_bounds__(256) void k_gemm2(const unsigned short* __restrict__ hb1,
                                               const float* __restrict__ W2,
                                               unsigned short* __restrict__ h2b) {
  __shared__ unsigned short As[64 * BKP2];
  __shared__ unsigned short Bs[48 * BKP2];
  const int t = threadIdx.x;
  const int r0 = blockIdx.x * 64;
  const int wave = t >> 6, lane = t & 63;
  const int quad = lane >> 4, mr = lane & 15;
  const int mrow0 = wave * 16;

  const int ar = t >> 2, aq = t & 3;
  int grow = r0 + ar; if (grow > NN - 1) grow = NN - 1;
  const us8* hrow = (const us8*)(hb1 + (size_t)grow * HID);
  #pragma unroll
  for (int i = 0; i < 4; ++i) {
    us8 v = hrow[aq + i * 4];
    *(us8*)&As[ar * BKP2 + aq * 8 + i * 32] = v;
  }
  if (t < 192) {
    int n = t >> 2, q = t & 3;
    #pragma unroll
    for (int kk = 0; kk < 32; ++kk) {
      int k = q * 32 + kk;
      float val = (n < NOUT) ? W2[k * NOUT + n] : 0.f;
      Bs[n * BKP2 + k] = f2bf(val);
    }
  }
  __syncthreads();

  const v4f vzero = {0.f, 0.f, 0.f, 0.f};
  v4f acc[3] = {vzero, vzero, vzero};
  #pragma unroll
  for (int ks = 0; ks < HID; ks += 32) {
    v8bf a = *(const v8bf*)&As[(mrow0 + mr) * BKP2 + ks + quad * 8];
    #pragma unroll
    for (int j = 0; j < 3; ++j) {
      v8bf b = *(const v8bf*)&Bs[(j * 16 + mr) * BKP2 + ks + quad * 8];
      acc[j] = __builtin_amdgcn_mfma_f32_16x16x32_bf16(a, b, acc[j], 0, 0, 0);
    }
  }
  #pragma unroll
  for (int j = 0; j < 3; ++j)
    #pragma unroll
    for (int rr = 0; rr < 4; ++rr) {
      int row = r0 + mrow0 + quad * 4 + rr;
      int col = j * 16 + mr;
      if (row < NN && col < NOUT) h2b[(size_t)row * H2P + col] = f2bf(acc[j][rr]);
    }
}

// ---------- SpMM2: 4 groups x 16 lanes (10 active), bf16 8B gathers ----------
// Same u32x4 bucket-word batching as spmm1.
__global__ __launch_bounds__(256) void k_spmm2(const unsigned short* __restrict__ h2b,
                                               const int* __restrict__ nxt,
                                               const unsigned int* __restrict__ bkt,
                                               const float* __restrict__ b2,
                                               float* __restrict__ out) {
  const int t = threadIdx.x, lane = t & 63;
  const int g = lane >> 4, ql = lane & 15;
  const int i = blockIdx.x * 4 + (t >> 6);
  if (i >= NN) return;
  const int act = (ql < 10);
  const int c0 = act ? ql * 4 : 0;             // clamp inactive lanes in-bounds
  int nE = nxt[(size_t)i * NXS]; if (nE > CAP) nE = CAP;
  const int m = (nE + 3 - g) >> 2;
  const unsigned int* ep = bkt + (size_t)i * CAP + g * 16;   // contiguous words

  const v2f z2 = {0.f, 0.f};
  v2f a0p[2] = {z2, z2};
  v2f a1p[2] = {z2, z2};
  int j = 0;
  for (; j + 3 < m; j += 4) {
    u32x4 pw = *(const u32x4*)&ep[j];          // one 16B load: 4 edge words
    int s0 = pw[0] & 0xFFFF, s1 = pw[1] & 0xFFFF;
    int s2 = pw[2] & 0xFFFF, s3 = pw[3] & 0xFFFF;
    v2f w0, w1, w2, w3;
    w0.x = w0.y = bf2f((unsigned short)(pw[0] >> 16));
    w1.x = w1.y = bf2f((unsigned short)(pw[1] >> 16));
    w2.x = w2.y = bf2f((unsigned short)(pw[2] >> 16));
    w3.x = w3.y = bf2f((unsigned short)(pw[3] >> 16));
    u32x2 h0 = *(const u32x2*)&h2b[(size_t)s0 * H2P + c0];
    u32x2 h1 = *(const u32x2*)&h2b[(size_t)s1 * H2P + c0];
    u32x2 h2 = *(const u32x2*)&h2b[(size_t)s2 * H2P + c0];
    u32x2 h3 = *(const u32x2*)&h2b[(size_t)s3 * H2P + c0];
    #pragma unroll
    for (int d = 0; d < 2; ++d) {
      a0p[d] += w0 * bfp2f(h0[d]);
      a1p[d] += w1 * bfp2f(h1[d]);
      a0p[d] += w2 * bfp2f(h2[d]);
      a1p[d] += w3 * bfp2f(h3[d]);
    }
  }
  for (; j < m; ++j) {
    unsigned int p = ep[j];
    int s = p & 0xFFFF;
    v2f w; w.x = w.y = bf2f((unsigned short)(p >> 16));
    u32x2 h = *(const u32x2*)&h2b[(size_t)s * H2P + c0];
    #pragma unroll
    for (int d = 0; d < 2; ++d) a0p[d] += w * bfp2f(h[d]);
  }
  float v[4];
  #pragma unroll
  for (int d = 0; d < 2; ++d) {
    v2f s = a0p[d] + a1p[d];
    v[2*d] = s.x; v[2*d+1] = s.y;
  }
  #pragma unroll
  for (int k = 0; k < 4; ++k) {
    v[k] += __shfl_xor(v[k], 16);
    v[k] += __shfl_xor(v[k], 32);
  }
  if (g == 0 && act) {
    const float4 bb = *(const float4*)&b2[c0];
    float4 o;
    o.x = v[0] + bb.x;
    o.y = v[1] + bb.y;
    o.z = v[2] + bb.z;
    o.w = v[3] + bb.w;
    *(float4*)&out[(size_t)i * NOUT + c0] = o;
  }
}

extern "C" void kernel_launch(void* const* d_in, const int* in_sizes, int n_in,
                              void* d_out, int out_size, void* d_ws, size_t ws_size,
                              hipStream_t stream) {
  const float* x   = (const float*)d_in[0];
  const float* W1  = (const float*)d_in[1];
  const float* b1  = (const float*)d_in[2];
  const float* W2  = (const float*)d_in[3];
  const float* b2  = (const float*)d_in[4];
  const float* ew  = (const float*)d_in[5];
  const float* msk = (const float*)d_in[6];
  const int* esrc  = (const int*)d_in[7];
  const int* edst  = (const int*)d_in[8];
  float* out = (float*)d_out;

  char* ws = (char*)d_ws;
  unsigned short* hb0 = (unsigned short*)ws; ws += (size_t)NN * HID * 2;   // 12.8 MB
  unsigned short* hb1 = (unsigned short*)ws; ws += (size_t)NN * HID * 2;   // 12.8 MB
  unsigned short* h2b = (unsigned short*)ws; ws += (size_t)NN * H2P * 2;   // 6.4 MB
  unsigned short* W1t = (unsigned short*)ws; ws += (size_t)HID * FIN * 2;  // 128 KB
  unsigned int* bkt   = (unsigned int*)ws;   ws += (size_t)NN * CAP * 4;   // 12.8 MB
  unsigned int* mpk   = (unsigned int*)ws;   ws += (size_t)NN * 4 * 4;     // 800 KB
  int* nxt            = (int*)ws;            ws += (size_t)NN * NXS * 4;   // 3.2 MB

  k_w1t  <<<(FIN * HID) / 256, 256, 0, stream>>>(W1, W1t, nxt);
  k_fused<<<GB1 + SB + MB, 256, 0, stream>>>(x, W1t, hb0,
                                             esrc, edst, ew, nxt, bkt,
                                             msk, mpk);
  k_spmm1<<<NN / 4, 256, 0, stream>>>(hb0, nxt, bkt, b1, mpk, hb1);
  k_gemm2<<<(NN + 63) / 64, 256, 0, stream>>>(hb1, W2, h2b);
  k_spmm2<<<(NN + 3) / 4, 256, 0, stream>>>(h2b, nxt, bkt, b2, out);
}

// Round 12
// 283.168 us; speedup vs baseline: 1.0887x; 1.0318x over previous
//
#include <hip/hip_runtime.h>

#define NN 50000
#define NE 800000
#define FIN 512
#define HID 128
#define NOUT 40
#define H2P 64          // padded h2 row (elements) -> 128B aligned rows
#define CAP 64          // bucket capacity per row (max degree ~36 for Poisson-16)
#define NXS 16          // nxt counter stride (ints) -> one counter per 64B line
#define GB1 782         // gemm1 blocks = ceil(NN/64)  (R3-exact)
#define EPB 2048        // edges per scatter block (8 per thread, ILP)
#define SB  391         // scatter blocks = ceil(NE/EPB)
#define MB  782         // maskpack blocks = ceil(NN*4/256)

typedef __bf16 v8bf __attribute__((ext_vector_type(8)));
typedef float  v4f  __attribute__((ext_vector_type(4)));
typedef float  v2f  __attribute__((ext_vector_type(2)));
typedef unsigned short us8 __attribute__((ext_vector_type(8)));
typedef unsigned short us4 __attribute__((ext_vector_type(4)));
typedef unsigned int   u32x4 __attribute__((ext_vector_type(4)));
typedef unsigned int   u32x2 __attribute__((ext_vector_type(2)));

static __device__ __forceinline__ unsigned short f2bf(float f) {
  union { float f; unsigned int u; } v; v.f = f;
  unsigned int r = v.u + 0x7FFFu + ((v.u >> 16) & 1u);
  return (unsigned short)(r >> 16);
}
static __device__ __forceinline__ float bf2f(unsigned short s) {
  union { unsigned int u; float f; } v; v.u = ((unsigned int)s) << 16;
  return v.f;
}
static __device__ __forceinline__ float u2f(unsigned int u) {
  union { unsigned int u; float f; } v; v.u = u;
  return v.f;
}
// dword of 2 bf16 -> float2 {lo, hi}; 2 VALU ops, feeds v_pk_fma_f32
static __device__ __forceinline__ v2f bfp2f(unsigned int u) {
  v2f r; r.x = u2f(u << 16); r.y = u2f(u & 0xFFFF0000u); return r;
}

// ---------- W1 [FIN][HID] f32 -> W1t [HID][FIN] bf16 ; also zero nxt ----------
__global__ void k_w1t(const float* __restrict__ W1, unsigned short* __restrict__ W1t,
                      int* __restrict__ nxt) {
  int id = blockIdx.x * 256 + threadIdx.x;   // 65536 threads
  int k = id >> 7;
  int n = id & 127;
  W1t[n * FIN + k] = f2bf(W1[k * HID + n]);
  if (id < NN) nxt[(size_t)id * NXS] = 0;    // one counter per 64B line
}

// ---- fused: GEMM1 [0,GB1) | scatter [GB1,GB1+SB) | maskpack [GB1+SB,+MB) ----
// R3-exact structure + R11 group-swizzled bucket writes (measured 292.2us).
#define BM1 64
#define BK1 64
#define BKP1 72
__global__ __launch_bounds__(256) void k_fused(
    const float* __restrict__ x, const unsigned short* __restrict__ W1t,
    unsigned short* __restrict__ hb0,
    const int* __restrict__ src, const int* __restrict__ dst,
    const float* __restrict__ w, int* __restrict__ nxt,
    unsigned int* __restrict__ bkt,
    const float* __restrict__ mask, unsigned int* __restrict__ mpk) {
  __shared__ unsigned short As[BM1 * BKP1];   // 9216 B
  __shared__ unsigned short Bs[HID * BKP1];   // 18432 B
  const int t = threadIdx.x;

  if (blockIdx.x >= GB1 + SB) {
    // ---------------- maskpack body: 4 uint words per row ----------------
    int id = (blockIdx.x - (GB1 + SB)) * 256 + t;
    if (id < NN * 4) {
      int row = id >> 2, seg = id & 3;
      const float4* mp = (const float4*)(mask + (size_t)row * HID + seg * 32);
      unsigned int bits = 0;
      #pragma unroll
      for (int q = 0; q < 8; ++q) {
        float4 v = mp[q];
        bits |= (v.x != 0.f ? 1u : 0u) << (q * 4);
        bits |= (v.y != 0.f ? 1u : 0u) << (q * 4 + 1);
        bits |= (v.z != 0.f ? 1u : 0u) << (q * 4 + 2);
        bits |= (v.w != 0.f ? 1u : 0u) << (q * 4 + 3);
      }
      mpk[(size_t)row * 4 + seg] = bits;
    }
    return;
  }

  if (blockIdx.x >= GB1) {
    // -------- scatter body: 8 edges/thread, independent atomics --------
    const int base = (blockIdx.x - GB1) * EPB + t;
    int   ii[8]; unsigned int pk[8]; int ok[8];
    #pragma unroll
    for (int k = 0; k < 8; ++k) {
      int e = base + k * 256;
      ok[k] = (e < NE);
      int ec = ok[k] ? e : (NE - 1);
      ii[k] = dst[ec];
      pk[k] = (unsigned int)src[ec] | ((unsigned int)f2bf(w[ec]) << 16);
    }
    int p[8];
    #pragma unroll
    for (int k = 0; k < 8; ++k)
      p[k] = ok[k] ? atomicAdd(&nxt[(size_t)ii[k] * NXS], 1) : CAP;
    #pragma unroll
    for (int k = 0; k < 8; ++k)
      if (p[k] < CAP) {
        int slot = ((p[k] & 3) << 4) + (p[k] >> 2);   // group-contiguous layout
        bkt[(size_t)ii[k] * CAP + slot] = pk[k];
      }
    return;
  }

  // ---------------- gemm1 body (R3-exact) ----------------
  const int r0 = blockIdx.x * BM1;
  const int wave = t >> 6, lane = t & 63;
  const int quad = lane >> 4, mr = lane & 15;
  const int mrow0 = (wave & 1) * 32;
  const int ncol0 = (wave >> 1) * 64;

  const int ar = t >> 2, aq = t & 3;
  int grow = r0 + ar; if (grow > NN - 1) grow = NN - 1;
  const float4* xrow = (const float4*)(x + (size_t)grow * FIN);
  const int bn = t >> 1, bh = t & 1;

  const v4f vzero = {0.f, 0.f, 0.f, 0.f};
  v4f acc[2][4];
  #pragma unroll
  for (int mi = 0; mi < 2; ++mi)
    #pragma unroll
    for (int j = 0; j < 4; ++j) acc[mi][j] = vzero;

  for (int k0 = 0; k0 < FIN; k0 += BK1) {
    float4 va[4];
    #pragma unroll
    for (int i = 0; i < 4; ++i) va[i] = xrow[(k0 >> 2) + aq + i * 4];
    us8 vb[4];
    const us8* bp = (const us8*)(W1t + bn * FIN + k0 + bh * 32);
    #pragma unroll
    for (int i = 0; i < 4; ++i) vb[i] = bp[i];

    __syncthreads();
    #pragma unroll
    for (int i = 0; i < 4; ++i) {
      us4 s; s.x = f2bf(va[i].x); s.y = f2bf(va[i].y);
             s.z = f2bf(va[i].z); s.w = f2bf(va[i].w);
      *(us4*)&As[ar * BKP1 + aq * 4 + i * 16] = s;
    }
    #pragma unroll
    for (int i = 0; i < 4; ++i)
      *(us8*)&Bs[bn * BKP1 + bh * 32 + i * 8] = vb[i];
    __syncthreads();

    #pragma unroll
    for (int ks = 0; ks < BK1; ks += 32) {
      v8bf a0 = *(const v8bf*)&As[(mrow0 + mr) * BKP1 + ks + quad * 8];
      v8bf a1 = *(const v8bf*)&As[(mrow0 + 16 + mr) * BKP1 + ks + quad * 8];
      #pragma unroll
      for (int j = 0; j < 4; ++j) {
        v8bf b = *(const v8bf*)&Bs[(ncol0 + j * 16 + mr) * BKP1 + ks + quad * 8];
        acc[0][j] = __builtin_amdgcn_mfma_f32_16x16x32_bf16(a0, b, acc[0][j], 0, 0, 0);
        acc[1][j] = __builtin_amdgcn_mfma_f32_16x16x32_bf16(a1, b, acc[1][j], 0, 0, 0);
      }
    }
  }

  #pragma unroll
  for (int mi = 0; mi < 2; ++mi)
    #pragma unroll
    for (int j = 0; j < 4; ++j)
      #pragma unroll
      for (int rr = 0; rr < 4; ++rr) {
        int row = r0 + mrow0 + mi * 16 + quad * 4 + rr;
        int col = ncol0 + j * 16 + mr;
        if (row < NN) hb0[(size_t)row * HID + col] = f2bf(acc[mi][j][rr]);
      }
}

// ---------- SpMM1: predicated 8-batch gather (no serial tail) ----------
// R11 win confirmed the gather chain is latency-bound. With degree~16, m~4:
// the old 4-batch + serial tail cost up to 5 L2 round trips. Now: ONE batch
// of 8 predicated edges (slots g*16..g*16+7 always in-bounds) -> 2 round
// trips flat. Invalid edges: s->0, w->0 via cndmask (row 0 is finite, so
// 0*finite=0; zeroing only w would risk NaN from poison rows). m>8 (degree
// >32/group, ~never at Poisson-16) falls into the old loop.
__global__ __launch_bounds__(256) void k_spmm1(const unsigned short* __restrict__ hb0,
                                               const int* __restrict__ nxt,
                                               const unsigned int* __restrict__ bkt,
                                               const float* __restrict__ b1,
                                               const unsigned int* __restrict__ mpk,
                                               unsigned short* __restrict__ hb1) {
  const int t = threadIdx.x, lane = t & 63, wv = t >> 6;
  const int g = lane >> 4, ql = lane & 15;
  const int i = blockIdx.x * 4 + wv;
  const int c0 = ql * 8;
  int nE = nxt[(size_t)i * NXS]; if (nE > CAP) nE = CAP;
  const int m = (nE + 3 - g) >> 2;             // edges handled by this group
  const unsigned int* ep = bkt + (size_t)i * CAP + g * 16;   // contiguous words

  const v2f z2 = {0.f, 0.f};
  v2f a0p[4] = {z2, z2, z2, z2};
  v2f a1p[4] = {z2, z2, z2, z2};

  // ---- predicated batch of 8 (covers m <= 8, i.e. ~all rows) ----
  u32x4 pwA = *(const u32x4*)&ep[0];
  u32x4 pwB = *(const u32x4*)&ep[4];
  int sA[4], sB[4];
  v2f wA[4], wB[4];
  #pragma unroll
  for (int k = 0; k < 4; ++k) {
    int vA = (k < m), vB = (k + 4 < m);
    sA[k] = vA ? (int)(pwA[k] & 0xFFFF) : 0;
    sB[k] = vB ? (int)(pwB[k] & 0xFFFF) : 0;
    float fA = vA ? bf2f((unsigned short)(pwA[k] >> 16)) : 0.f;
    float fB = vB ? bf2f((unsigned short)(pwB[k] >> 16)) : 0.f;
    wA[k].x = wA[k].y = fA;
    wB[k].x = wB[k].y = fB;
  }
  u32x4 hA[4], hB[4];
  #pragma unroll
  for (int k = 0; k < 4; ++k) {
    hA[k] = *(const u32x4*)&hb0[(size_t)sA[k] * HID + c0];
    hB[k] = *(const u32x4*)&hb0[(size_t)sB[k] * HID + c0];
  }
  #pragma unroll
  for (int k = 0; k < 4; ++k)
    #pragma unroll
    for (int d = 0; d < 4; ++d) {
      a0p[d] += wA[k] * bfp2f(hA[k][d]);
      a1p[d] += wB[k] * bfp2f(hB[k][d]);
    }

  // ---- rare continuation for m > 8 ----
  int j = 8;
  for (; j + 3 < m; j += 4) {
    u32x4 pw = *(const u32x4*)&ep[j];
    int s0 = pw[0] & 0xFFFF, s1 = pw[1] & 0xFFFF;
    int s2 = pw[2] & 0xFFFF, s3 = pw[3] & 0xFFFF;
    v2f w0, w1, w2, w3;
    w0.x = w0.y = bf2f((unsigned short)(pw[0] >> 16));
    w1.x = w1.y = bf2f((unsigned short)(pw[1] >> 16));
    w2.x = w2.y = bf2f((unsigned short)(pw[2] >> 16));
    w3.x = w3.y = bf2f((unsigned short)(pw[3] >> 16));
    u32x4 h0 = *(const u32x4*)&hb0[(size_t)s0 * HID + c0];
    u32x4 h1 = *(const u32x4*)&hb0[(size_t)s1 * HID + c0];
    u32x4 h2 = *(const u32x4*)&hb0[(size_t)s2 * HID + c0];
    u32x4 h3 = *(const u32x4*)&hb0[(size_t)s3 * HID + c0];
    #pragma unroll
    for (int d = 0; d < 4; ++d) {
      a0p[d] += w0 * bfp2f(h0[d]);
      a1p[d] += w1 * bfp2f(h1[d]);
      a0p[d] += w2 * bfp2f(h2[d]);
      a1p[d] += w3 * bfp2f(h3[d]);
    }
  }
  for (; j < m; ++j) {
    unsigned int p = ep[j];
    int s = p & 0xFFFF;
    v2f w; w.x = w.y = bf2f((unsigned short)(p >> 16));
    u32x4 h = *(const u32x4*)&hb0[(size_t)s * HID + c0];
    #pragma unroll
    for (int d = 0; d < 4; ++d) a0p[d] += w * bfp2f(h[d]);
  }

  float v[8];
  #pragma unroll
  for (int d = 0; d < 4; ++d) {
    v2f s = a0p[d] + a1p[d];
    v[2*d] = s.x; v[2*d+1] = s.y;
  }
  #pragma unroll
  for (int k = 0; k < 8; ++k) {
    v[k] += __shfl_xor(v[k], 16);
    v[k] += __shfl_xor(v[k], 32);
  }
  if (g == 0) {
    unsigned int word = mpk[(size_t)i * 4 + (ql >> 2)];
    unsigned int byte = (word >> ((ql & 3) * 8)) & 0xFFu;
    const float4 bbA = *(const float4*)&b1[c0];
    const float4 bbB = *(const float4*)&b1[c0 + 4];
    float bb[8] = {bbA.x, bbA.y, bbA.z, bbA.w, bbB.x, bbB.y, bbB.z, bbB.w};
    us8 o;
    #pragma unroll
    for (int k = 0; k < 8; ++k) {
      float r = ((byte >> k) & 1u) ? fmaxf(v[k] + bb[k], 0.f) * 2.0f : 0.f;
      o[k] = f2bf(r);
    }
    *(us8*)&hb1[(size_t)i * HID + c0] = o;
  }
}

// ------ GEMM2: h2b[NN][H2P=64] = bf16(hb1 @ W2), rows 128B-aligned ------
#define BKP2 136
__global__ __launch_bounds__(256) void k_gemm2(const unsigned short* __restrict__ hb1,
                                               const float* __restrict__ W2,
                                               unsigned short* __restrict__ h2b) {
  __shared__ unsigned short As[64 * BKP2];
  __shared__ unsigned short Bs[48 * BKP2];
  const int t = threadIdx.x;
  const int r0 = blockIdx.x * 64;
  const int wave = t >> 6, lane = t & 63;
  const int quad = lane >> 4, mr = lane & 15;
  const int mrow0 = wave * 16;

  const int ar = t >> 2, aq = t & 3;
  int grow = r0 + ar; if (grow > NN - 1) grow = NN - 1;
  const us8* hrow = (const us8*)(hb1 + (size_t)grow * HID);
  #pragma unroll
  for (int i = 0; i < 4; ++i) {
    us8 v = hrow[aq + i * 4];
    *(us8*)&As[ar * BKP2 + aq * 8 + i * 32] = v;
  }
  if (t < 192) {
    int n = t >> 2, q = t & 3;
    #pragma unroll
    for (int kk = 0; kk < 32; ++kk) {
      int k = q * 32 + kk;
      float val = (n < NOUT) ? W2[k * NOUT + n] : 0.f;
      Bs[n * BKP2 + k] = f2bf(val);
    }
  }
  __syncthreads();

  const v4f vzero = {0.f, 0.f, 0.f, 0.f};
  v4f acc[3] = {vzero, vzero, vzero};
  #pragma unroll
  for (int ks = 0; ks < HID; ks += 32) {
    v8bf a = *(const v8bf*)&As[(mrow0 + mr) * BKP2 + ks + quad * 8];
    #pragma unroll
    for (int j = 0; j < 3; ++j) {
      v8bf b = *(const v8bf*)&Bs[(j * 16 + mr) * BKP2 + ks + quad * 8];
      acc[j] = __builtin_amdgcn_mfma_f32_16x16x32_bf16(a, b, acc[j], 0, 0, 0);
    }
  }
  #pragma unroll
  for (int j = 0; j < 3; ++j)
    #pragma unroll
    for (int rr = 0; rr < 4; ++rr) {
      int row = r0 + mrow0 + quad * 4 + rr;
      int col = j * 16 + mr;
      if (row < NN && col < NOUT) h2b[(size_t)row * H2P + col] = f2bf(acc[j][rr]);
    }
}

// ---------- SpMM2: predicated 8-batch gather (same scheme as spmm1) ----------
__global__ __launch_bounds__(256) void k_spmm2(const unsigned short* __restrict__ h2b,
                                               const int* __restrict__ nxt,
                                               const unsigned int* __restrict__ bkt,
                                               const float* __restrict__ b2,
                                               float* __restrict__ out) {
  const int t = threadIdx.x, lane = t & 63;
  const int g = lane >> 4, ql = lane & 15;
  const int i = blockIdx.x * 4 + (t >> 6);
  if (i >= NN) return;
  const int act = (ql < 10);
  const int c0 = act ? ql * 4 : 0;             // clamp inactive lanes in-bounds
  int nE = nxt[(size_t)i * NXS]; if (nE > CAP) nE = CAP;
  const int m = (nE + 3 - g) >> 2;
  const unsigned int* ep = bkt + (size_t)i * CAP + g * 16;   // contiguous words

  const v2f z2 = {0.f, 0.f};
  v2f a0p[2] = {z2, z2};
  v2f a1p[2] = {z2, z2};

  // ---- predicated batch of 8 ----
  u32x4 pwA = *(const u32x4*)&ep[0];
  u32x4 pwB = *(const u32x4*)&ep[4];
  int sA[4], sB[4];
  v2f wA[4], wB[4];
  #pragma unroll
  for (int k = 0; k < 4; ++k) {
    int vA = (k < m), vB = (k + 4 < m);
    sA[k] = vA ? (int)(pwA[k] & 0xFFFF) : 0;
    sB[k] = vB ? (int)(pwB[k] & 0xFFFF) : 0;
    float fA = vA ? bf2f((unsigned short)(pwA[k] >> 16)) : 0.f;
    float fB = vB ? bf2f((unsigned short)(pwB[k] >> 16)) : 0.f;
    wA[k].x = wA[k].y = fA;
    wB[k].x = wB[k].y = fB;
  }
  u32x2 hA[4], hB[4];
  #pragma unroll
  for (int k = 0; k < 4; ++k) {
    hA[k] = *(const u32x2*)&h2b[(size_t)sA[k] * H2P + c0];
    hB[k] = *(const u32x2*)&h2b[(size_t)sB[k] * H2P + c0];
  }
  #pragma unroll
  for (int k = 0; k < 4; ++k)
    #pragma unroll
    for (int d = 0; d < 2; ++d) {
      a0p[d] += wA[k] * bfp2f(hA[k][d]);
      a1p[d] += wB[k] * bfp2f(hB[k][d]);
    }

  // ---- rare continuation for m > 8 ----
  int j = 8;
  for (; j + 3 < m; j += 4) {
    u32x4 pw = *(const u32x4*)&ep[j];
    int s0 = pw[0] & 0xFFFF, s1 = pw[1] & 0xFFFF;
    int s2 = pw[2] & 0xFFFF, s3 = pw[3] & 0xFFFF;
    v2f w0, w1, w2, w3;
    w0.x = w0.y = bf2f((unsigned short)(pw[0] >> 16));
    w1.x = w1.y = bf2f((unsigned short)(pw[1] >> 16));
    w2.x = w2.y = bf2f((unsigned short)(pw[2] >> 16));
    w3.x = w3.y = bf2f((unsigned short)(pw[3] >> 16));
    u32x2 h0 = *(const u32x2*)&h2b[(size_t)s0 * H2P + c0];
    u32x2 h1 = *(const u32x2*)&h2b[(size_t)s1 * H2P + c0];
    u32x2 h2 = *(const u32x2*)&h2b[(size_t)s2 * H2P + c0];
    u32x2 h3 = *(const u32x2*)&h2b[(size_t)s3 * H2P + c0];
    #pragma unroll
    for (int d = 0; d < 2; ++d) {
      a0p[d] += w0 * bfp2f(h0[d]);
      a1p[d] += w1 * bfp2f(h1[d]);
      a0p[d] += w2 * bfp2f(h2[d]);
      a1p[d] += w3 * bfp2f(h3[d]);
    }
  }
  for (; j < m; ++j) {
    unsigned int p = ep[j];
    int s = p & 0xFFFF;
    v2f w; w.x = w.y = bf2f((unsigned short)(p >> 16));
    u32x2 h = *(const u32x2*)&h2b[(size_t)s * H2P + c0];
    #pragma unroll
    for (int d = 0; d < 2; ++d) a0p[d] += w * bfp2f(h[d]);
  }

  float v[4];
  #pragma unroll
  for (int d = 0; d < 2; ++d) {
    v2f s = a0p[d] + a1p[d];
    v[2*d] = s.x; v[2*d+1] = s.y;
  }
  #pragma unroll
  for (int k = 0; k < 4; ++k) {
    v[k] += __shfl_xor(v[k], 16);
    v[k] += __shfl_xor(v[k], 32);
  }
  if (g == 0 && act) {
    const float4 bb = *(const float4*)&b2[c0];
    float4 o;
    o.x = v[0] + bb.x;
    o.y = v[1] + bb.y;
    o.z = v[2] + bb.z;
    o.w = v[3] + bb.w;
    *(float4*)&out[(size_t)i * NOUT + c0] = o;
  }
}

extern "C" void kernel_launch(void* const* d_in, const int* in_sizes, int n_in,
                              void* d_out, int out_size, void* d_ws, size_t ws_size,
                              hipStream_t stream) {
  const float* x   = (const float*)d_in[0];
  const float* W1  = (const float*)d_in[1];
  const float* b1  = (const float*)d_in[2];
  const float* W2  = (const float*)d_in[3];
  const float* b2  = (const float*)d_in[4];
  const float* ew  = (const float*)d_in[5];
  const float* msk = (const float*)d_in[6];
  const int* esrc  = (const int*)d_in[7];
  const int* edst  = (const int*)d_in[8];
  float* out = (float*)d_out;

  char* ws = (char*)d_ws;
  unsigned short* hb0 = (unsigned short*)ws; ws += (size_t)NN * HID * 2;   // 12.8 MB
  unsigned short* hb1 = (unsigned short*)ws; ws += (size_t)NN * HID * 2;   // 12.8 MB
  unsigned short* h2b = (unsigned short*)ws; ws += (size_t)NN * H2P * 2;   // 6.4 MB
  unsigned short* W1t = (unsigned short*)ws; ws += (size_t)HID * FIN * 2;  // 128 KB
  unsigned int* bkt   = (unsigned int*)ws;   ws += (size_t)NN * CAP * 4;   // 12.8 MB
  unsigned int* mpk   = (unsigned int*)ws;   ws += (size_t)NN * 4 * 4;     // 800 KB
  int* nxt            = (int*)ws;            ws += (size_t)NN * NXS * 4;   // 3.2 MB

  k_w1t  <<<(FIN * HID) / 256, 256, 0, stream>>>(W1, W1t, nxt);
  k_fused<<<GB1 + SB + MB, 256, 0, stream>>>(x, W1t, hb0,
                                             esrc, edst, ew, nxt, bkt,
                                             msk, mpk);
  k_spmm1<<<NN / 4, 256, 0, stream>>>(hb0, nxt, bkt, b1, mpk, hb1);
  k_gemm2<<<(NN + 63) / 64, 256, 0, stream>>>(hb1, W2, h2b);
  k_spmm2<<<(NN + 3) / 4, 256, 0, stream>>>(h2b, nxt, bkt, b2, out);
}